// Round 9
// baseline (549.948 us; speedup 1.0000x reference)
//
#include <hip/hip_runtime.h>
#include <stdint.h>

#define B_ 16
#define S_ 64
#define M_ 4096
#define D_ 1024
#define H_ 16
#define DH_ 64

typedef unsigned short ushort_t;
typedef __attribute__((ext_vector_type(8))) __bf16 bfrag;   // 8 bf16 = 4 VGPRs
typedef __attribute__((ext_vector_type(4))) float f32x4;

// fp32 -> bf16 RNE
__device__ __forceinline__ ushort_t f2bf(float f) {
  union { float f; uint32_t u; } v; v.f = f;
  uint32_t r = v.u + 0x7fffu + ((v.u >> 16) & 1u);
  return (ushort_t)(r >> 16);
}

__device__ __forceinline__ void gload_lds16(const void* g, void* l) {
  __builtin_amdgcn_global_load_lds((const __attribute__((address_space(1))) void*)g,
                                   (__attribute__((address_space(3))) void*)l, 16, 0, 0);
}

__device__ __forceinline__ f32x4 mfma16x16x32(bfrag a, bfrag b, f32x4 c) {
  return __builtin_amdgcn_mfma_f32_16x16x32_bf16(a, b, c, 0, 0, 0);
}

// epilogue-region swizzle: granule ^= fsw(row); fsw>>1 injective over klo groups
__device__ __forceinline__ int fsw(int r) { return (((r >> 2) & 3) << 1) | (r & 1); }

// ---------------- LayerNorm rows (1024 wide) -> bf16 ----------------
__global__ __launch_bounds__(256) void ln_rows_kernel(
    const float* __restrict__ x, const float* __restrict__ g,
    const float* __restrict__ bta, ushort_t* __restrict__ out) {
  const int row = blockIdx.x;
  const int t = threadIdx.x;
  const float4* xr = (const float4*)(x + (size_t)row * D_);
  float4 v = xr[t];
  float s = v.x + v.y + v.z + v.w;
  float ss = v.x * v.x + v.y * v.y + v.z * v.z + v.w * v.w;
#pragma unroll
  for (int o = 32; o >= 1; o >>= 1) { s += __shfl_down(s, o); ss += __shfl_down(ss, o); }
  __shared__ float red[16];
  const int wid = t >> 6;
  if ((t & 63) == 0) { red[wid] = s; red[8 + wid] = ss; }
  __syncthreads();
  float tot = red[0] + red[1] + red[2] + red[3];
  float tot2 = red[8] + red[9] + red[10] + red[11];
  float mu = tot * (1.0f / D_);
  float var = tot2 * (1.0f / D_) - mu * mu;
  float rstd = rsqrtf(var + 1e-5f);
  float4 gg = ((const float4*)g)[t];
  float4 bb = ((const float4*)bta)[t];
  ushort_t ob[4];
  ob[0] = f2bf((v.x - mu) * rstd * gg.x + bb.x);
  ob[1] = f2bf((v.y - mu) * rstd * gg.y + bb.y);
  ob[2] = f2bf((v.z - mu) * rstd * gg.z + bb.z);
  ob[3] = f2bf((v.w - mu) * rstd * gg.w + bb.w);
  *(uint2*)(out + (size_t)row * D_ + t * 4) = *(const uint2*)ob;
}

// ---------------- W[K=1024][N] fp32 -> WT[N][1024] bf16 (scaled) ----------------
__global__ void transpose_cast_kernel(const float* __restrict__ W, ushort_t* __restrict__ WT,
                                      int N, float scale) {
  __shared__ float tile[32][33];
  const int n0 = blockIdx.x * 32, k0 = blockIdx.y * 32;
  const int tx = threadIdx.x, ty = threadIdx.y;
#pragma unroll
  for (int i = ty; i < 32; i += 8)
    tile[i][tx] = W[(size_t)(k0 + i) * N + n0 + tx];
  __syncthreads();
#pragma unroll
  for (int i = ty; i < 32; i += 8)
    WT[(size_t)(n0 + i) * D_ + k0 + tx] = f2bf(tile[tx][i] * scale);
}

// ---------------- kv GEMM (small, 4.3 GF): 128x128, scatter to (b,h,s,d) ----------
__global__ __launch_bounds__(256) void gemm_kv_kernel(
    const ushort_t* __restrict__ A, const ushort_t* __restrict__ Bt,
    ushort_t* __restrict__ kb, ushort_t* __restrict__ vb) {
  __shared__ __align__(16) ushort_t sA[128 * 32];
  __shared__ __align__(16) ushort_t sB[128 * 32];
  const int tid = threadIdx.x, wid = tid >> 6, lane = tid & 63;
  const size_t arow0 = (size_t)blockIdx.x * 128;
  const size_t brow0 = (size_t)blockIdx.y * 128;
  const int wr = (wid >> 1) * 64, wc = (wid & 1) * 64;
  const int srow = tid >> 2, scol = (tid & 3) * 8;
  const ushort_t* ga = A + (arow0 + srow) * (size_t)D_ + scol;
  const ushort_t* gb = Bt + (brow0 + srow) * (size_t)D_ + scol;
  const int frow = lane & 15, kslot = (lane >> 4) * 8;
  f32x4 acc[4][4] = {};
  for (int k0 = 0; k0 < D_; k0 += 32) {
    gload_lds16(ga, sA + wid * 512);
    gload_lds16(ga + 64 * (size_t)D_, sA + 2048 + wid * 512);
    gload_lds16(gb, sB + wid * 512);
    gload_lds16(gb + 64 * (size_t)D_, sB + 2048 + wid * 512);
    ga += 32; gb += 32;
    __syncthreads();
    bfrag af[4], bfv[4];
#pragma unroll
    for (int m = 0; m < 4; ++m)
      af[m] = *(const bfrag*)&sA[(wr + m * 16 + frow) * 32 + kslot];
#pragma unroll
    for (int n = 0; n < 4; ++n)
      bfv[n] = *(const bfrag*)&sB[(wc + n * 16 + frow) * 32 + kslot];
#pragma unroll
    for (int m = 0; m < 4; ++m)
#pragma unroll
      for (int n = 0; n < 4; ++n)
        acc[m][n] = mfma16x16x32(af[m], bfv[n], acc[m][n]);
    __syncthreads();
  }
  const int erow = (lane >> 4) * 4, ecol = lane & 15;
#pragma unroll
  for (int m = 0; m < 4; ++m)
#pragma unroll
    for (int n = 0; n < 4; ++n)
#pragma unroll
      for (int r = 0; r < 4; ++r) {
        size_t i = arow0 + wr + m * 16 + erow + r;
        int bb = (int)(i >> 6), s = (int)(i & 63);
        size_t n2 = brow0 + wc + n * 16 + ecol;
        ushort_t val = f2bf(acc[m][n][r]);
        ushort_t* dst = (n2 < 1024) ? kb : vb;
        size_t hh = (n2 & 1023) >> 6, d = n2 & 63;
        dst[(((size_t)bb * H_ + hh) * S_ + s) * DH_ + d] = val;
      }
}

// ============== m97-replica 128x128 GEMM, 3 blocks/CU, C = A * Bt^T ===============
// R3-R8 lesson: every deep-pipelined single-block-per-CU schedule lands at the
// 2-phase-class ~660TF ceiling (m230/m233). The documented plain-HIP mechanism
// past it is m97: ~3 INDEPENDENT blocks/CU whose waves cover each other's
// barrier drains (m114/m98 - MfmaUtil 37% with zero pipelining tricks).
// Geometry: 128x128 tile, 4 waves 2x2 (per-wave 64x64, acc=64 AGPR), BK=32,
// single-buffered 16KB staging LDS + 32KB epilogue scratch = 48KB/block.
// __launch_bounds__(256,3) caps VGPR<=170 -> 3 waves/SIMD; 48KB*3=144<=160KB.
// Plain __syncthreads() (compiler drains vmcnt - by design; other blocks cover).
// MODE 0: epilogue = fp32 C store; MODE 1: fused attention (wave = head x 64 rows).
template <int MODE>
__global__ __launch_bounds__(256, 3) void gemm97_kernel(
    const ushort_t* __restrict__ A, const ushort_t* __restrict__ Bt,
    const ushort_t* __restrict__ kbuf, const ushort_t* __restrict__ vbuf,
    void* __restrict__ Cout) {
  __shared__ __align__(16) ushort_t lds[24576];  // 48KB: sA 8K | sB 8K | W 4x8K
  ushort_t* const sA = lds;          // [128 rows][32 k] granule-swizzled
  ushort_t* const sB = lds + 4096;
  const int tid = threadIdx.x, wid = tid >> 6, lane = tid & 63;
  const int frow = lane & 15, klo = lane >> 4;
  const int wr = (wid >> 1) * 64, wc = (wid & 1) * 64;

  // chunked XCD map: 4096 = 8 x 512; consecutive l share mblk (A-panel L2 reuse)
  const int l = ((int)blockIdx.x & 7) * 512 + ((int)blockIdx.x >> 3);
  const int mblk = l >> 3, nblk = l & 7;
  const size_t arow0 = (size_t)mblk * 128;
  const size_t bcol0 = (size_t)nblk * 128;

  // staging: thread covers rows {tid>>2, (tid>>2)+64}, stored granule tid&3,
  // source granule swizzled ^((row>>1)&3) so LDS dst stays linear (m173 pattern)
  const int r0 = tid >> 2;
  const int gsrc = (tid & 3) ^ ((tid >> 3) & 3);
  const ushort_t* gA = A + (arow0 + r0) * (size_t)D_ + gsrc * 8;
  const ushort_t* gB = Bt + (bcol0 + r0) * (size_t)D_ + gsrc * 8;
  // ds_read swizzled granule offset (row bits1-2 == frow bits1-2 for 16-aligned rows)
  const int rasw = (klo ^ ((frow >> 1) & 3)) * 8;

  f32x4 acc[4][4] = {};
  for (int k0 = 0; k0 < 32; ++k0) {
    gload_lds16(gA, sA + wid * 512);
    gload_lds16(gA + 64 * (size_t)D_, sA + 2048 + wid * 512);
    gload_lds16(gB, sB + wid * 512);
    gload_lds16(gB + 64 * (size_t)D_, sB + 2048 + wid * 512);
    gA += 32; gB += 32;
    __syncthreads();
    bfrag a_[4], b_[4];
#pragma unroll
    for (int mf = 0; mf < 4; ++mf)
      a_[mf] = *(const bfrag*)&sA[(wr + mf * 16 + frow) * 32 + rasw];
#pragma unroll
    for (int nf = 0; nf < 4; ++nf)
      b_[nf] = *(const bfrag*)&sB[(wc + nf * 16 + frow) * 32 + rasw];
#pragma unroll
    for (int mf = 0; mf < 4; ++mf)
#pragma unroll
      for (int nf = 0; nf < 4; ++nf)
        acc[mf][nf] = mfma16x16x32(a_[mf], b_[nf], acc[mf][nf]);
    __syncthreads();
  }

  if constexpr (MODE == 0) {
    // ---------------- epilogue: fp32 C store (rows = m*16 + klo*4 + r) ----------
    float* C = (float*)Cout;
#pragma unroll
    for (int m = 0; m < 4; ++m)
#pragma unroll
      for (int n = 0; n < 4; ++n)
#pragma unroll
        for (int r = 0; r < 4; ++r)
          C[(arow0 + wr + m * 16 + klo * 4 + r) * 1024 + bcol0 + wc + n * 16 + frow] =
              acc[m][n][r];
  } else {
    // ---------------- epilogue: fused attention (wave = one head x 64 rows) ------
    ushort_t* W = &lds[8192 + wid * 4096];  // per-wave [64][64] bf16, granule ^= fsw(row)
    ushort_t* out1 = (ushort_t*)Cout;
    const int head = nblk * 2 + (wid & 1);
    const int bbatch = mblk >> 5;
    const size_t kvbase = ((size_t)bbatch * H_ + head) * (size_t)(S_ * DH_);

    // q -> W (acc dies here, freeing AGPRs before kb/vb loads)
#pragma unroll
    for (int m2 = 0; m2 < 4; ++m2)
#pragma unroll
      for (int r = 0; r < 4; ++r) {
        const int row = m2 * 16 + klo * 4 + r;
        const int fs = fsw(row);
#pragma unroll
        for (int n = 0; n < 4; ++n) {
          const int cc = n * 16 + frow;
          W[row * 64 + ((((cc >> 3) ^ fs) << 3) | (cc & 7))] = f2bf(acc[m2][n][r]);
        }
      }
    // sim = q @ K^T
    bfrag kb[4][2];
#pragma unroll
    for (int nf = 0; nf < 4; ++nf)
#pragma unroll
      for (int kk = 0; kk < 2; ++kk)
        kb[nf][kk] = *(const bfrag*)&kbuf[kvbase + (nf * 16 + frow) * 64 + kk * 32 + klo * 8];
    f32x4 s[4][4] = {};
#pragma unroll
    for (int m2 = 0; m2 < 4; ++m2) {
      const int row = m2 * 16 + frow;
      const int fs = fsw(row);
#pragma unroll
      for (int kk = 0; kk < 2; ++kk) {
        bfrag qa = *(const bfrag*)&W[row * 64 + (((kk * 4 + klo) ^ fs) << 3)];
#pragma unroll
        for (int nf = 0; nf < 4; ++nf)
          s[m2][nf] = mfma16x16x32(qa, kb[nf][kk], s[m2][nf]);
      }
    }
    // softmax over 64 keys (row in one 16-lane group, 4 keys/lane/frag)
#pragma unroll
    for (int m2 = 0; m2 < 4; ++m2)
#pragma unroll
      for (int r = 0; r < 4; ++r) {
        float a0 = s[m2][0][r], a1 = s[m2][1][r], a2 = s[m2][2][r], a3 = s[m2][3][r];
        float mx = fmaxf(fmaxf(a0, a1), fmaxf(a2, a3));
#pragma unroll
        for (int o = 1; o < 16; o <<= 1) mx = fmaxf(mx, __shfl_xor(mx, o));
        a0 = __expf(a0 - mx); a1 = __expf(a1 - mx);
        a2 = __expf(a2 - mx); a3 = __expf(a3 - mx);
        float sm = (a0 + a1) + (a2 + a3);
#pragma unroll
        for (int o = 1; o < 16; o <<= 1) sm += __shfl_xor(sm, o);
        const float inv = 1.0f / sm;
        s[m2][0][r] = a0 * inv; s[m2][1][r] = a1 * inv;
        s[m2][2][r] = a2 * inv; s[m2][3][r] = a3 * inv;
      }
    // P -> W (overwrite q; wave-private, in-order LDS)
#pragma unroll
    for (int m2 = 0; m2 < 4; ++m2)
#pragma unroll
      for (int r = 0; r < 4; ++r) {
        const int row = m2 * 16 + klo * 4 + r;
        const int fs = fsw(row);
#pragma unroll
        for (int n = 0; n < 4; ++n) {
          const int cc = n * 16 + frow;
          W[row * 64 + ((((cc >> 3) ^ fs) << 3) | (cc & 7))] = f2bf(s[m2][n][r]);
        }
      }
    // out1_head = attn @ "V^T" (einsum quirk: contract attn-keys with V dims)
    bfrag vb[4][2];
#pragma unroll
    for (int nf = 0; nf < 4; ++nf)
#pragma unroll
      for (int kk = 0; kk < 2; ++kk)
        vb[nf][kk] = *(const bfrag*)&vbuf[kvbase + (nf * 16 + frow) * 64 + kk * 32 + klo * 8];
    f32x4 o[4][4] = {};
#pragma unroll
    for (int m2 = 0; m2 < 4; ++m2) {
      const int row = m2 * 16 + frow;
      const int fs = fsw(row);
#pragma unroll
      for (int kk = 0; kk < 2; ++kk) {
        bfrag pa = *(const bfrag*)&W[row * 64 + (((kk * 4 + klo) ^ fs) << 3)];
#pragma unroll
        for (int nf = 0; nf < 4; ++nf)
          o[m2][nf] = mfma16x16x32(pa, vb[nf][kk], o[m2][nf]);
      }
    }
    // o -> W then coalesced uint4 stores
#pragma unroll
    for (int m2 = 0; m2 < 4; ++m2)
#pragma unroll
      for (int r = 0; r < 4; ++r) {
        const int row = m2 * 16 + klo * 4 + r;
        const int fs = fsw(row);
#pragma unroll
        for (int n = 0; n < 4; ++n) {
          const int cc = n * 16 + frow;
          W[row * 64 + ((((cc >> 3) ^ fs) << 3) | (cc & 7))] = f2bf(o[m2][n][r]);
        }
      }
    const size_t grow0 = arow0 + wr;
#pragma unroll
    for (int it = 0; it < 8; ++it) {
      const int idx = it * 64 + lane;
      const int rr = idx >> 3, gs = idx & 7;
      const int gcol = (gs ^ fsw(rr)) << 3;
      *(uint4*)&out1[(grow0 + rr) * 1024 + head * 64 + gcol] =
          *(const uint4*)&W[rr * 64 + gs * 8];
    }
  }
}

// -------------------------------- launch --------------------------------
extern "C" void kernel_launch(void* const* d_in, const int* in_sizes, int n_in,
                              void* d_out, int out_size, void* d_ws, size_t ws_size,
                              hipStream_t stream) {
  const float* x = (const float*)d_in[0];
  const float* lat = (const float*)d_in[1];
  const float* lxg = (const float*)d_in[2];
  const float* lxb = (const float*)d_in[3];
  const float* llg = (const float*)d_in[4];
  const float* llb = (const float*)d_in[5];
  const float* Wq = (const float*)d_in[6];
  const float* Wkv = (const float*)d_in[7];
  const float* Wout = (const float*)d_in[8];
  float* out = (float*)d_out;
  char* ws = (char*)d_ws;

  // ws layout (142MB): xn 2MB | wqT 2MB | wkvT 4MB | woT 2MB | k 2MB | v 2MB | out1 128MB
  ushort_t* xn = (ushort_t*)(ws);
  ushort_t* wqT = (ushort_t*)(ws + (2ull << 20));
  ushort_t* wkvT = (ushort_t*)(ws + (4ull << 20));
  ushort_t* woT = (ushort_t*)(ws + (8ull << 20));
  ushort_t* kbuf = (ushort_t*)(ws + (10ull << 20));
  ushort_t* vbuf = (ushort_t*)(ws + (12ull << 20));
  ushort_t* out1 = (ushort_t*)(ws + (14ull << 20));
  // lnl (bf16, 128MB) lives in d_out's first half: dead before final GEMM writes d_out
  ushort_t* lnl = (ushort_t*)d_out;

  dim3 tb(32, 8);
  transpose_cast_kernel<<<dim3(1024 / 32, 32), tb, 0, stream>>>(Wq, wqT, 1024, 0.125f);
  transpose_cast_kernel<<<dim3(2048 / 32, 32), tb, 0, stream>>>(Wkv, wkvT, 2048, 1.0f);
  transpose_cast_kernel<<<dim3(1024 / 32, 32), tb, 0, stream>>>(Wout, woT, 1024, 1.0f);
  ln_rows_kernel<<<B_ * S_, 256, 0, stream>>>(x, lxg, lxb, xn);
  ln_rows_kernel<<<B_ * M_, 256, 0, stream>>>(lat, llg, llb, lnl);
  gemm_kv_kernel<<<dim3(8, 16), 256, 0, stream>>>(xn, wkvT, kbuf, vbuf);
  gemm97_kernel<1><<<4096, 256, 0, stream>>>(lnl, wqT, kbuf, vbuf, out1);
  gemm97_kernel<0><<<4096, 256, 0, stream>>>(out1, woT, nullptr, nullptr, out);
}